// Round 8
// baseline (1701.942 us; speedup 1.0000x reference)
//
#include <hip/hip_runtime.h>
#include <math.h>

#define D 64

__device__ __forceinline__ float bf2f(unsigned short u) {
    union { unsigned int i; float f; } v; v.i = ((unsigned int)u) << 16; return v.f;
}
__device__ __forceinline__ unsigned short f2bf(float f) {
    union { float f; unsigned int i; } v; v.f = f;
    unsigned int r = v.i + 0x7FFFu + ((v.i >> 16) & 1u);
    return (unsigned short)(r >> 16);
}

// ============================ initial gather (both tables, one launch) ============================
__global__ __launch_bounds__(256) void k_gather2(const float* __restrict__ ue,
                                                 const float* __restrict__ ie,
                                                 const int* __restrict__ uid,
                                                 const int* __restrict__ iid,
                                                 float* __restrict__ uh0,
                                                 float* __restrict__ ih0, int NU, int NI) {
    int i = blockIdx.x * blockDim.x + threadIdx.x;
    if (i >= (NU + NI) * D) return;
    int r = i >> 6, c = i & 63;
    if (r < NU) uh0[(size_t)r * D + c] = ue[(size_t)uid[r] * D + c];
    else { int j = r - NU; ih0[(size_t)j * D + c] = ie[(size_t)iid[j] * D + c]; }
}

// ============================ CSR build (both relations per launch) ============================
__global__ __launch_bounds__(256) void k_hist2(const int* __restrict__ bd,
                                               const int* __restrict__ pd,
                                               int* __restrict__ cu, int* __restrict__ ci, int E) {
    for (int i = blockIdx.x * blockDim.x + threadIdx.x; i < 2 * E; i += gridDim.x * blockDim.x) {
        if (i < E) atomicAdd(&cu[bd[i]], 1);
        else       atomicAdd(&ci[pd[i - E]], 1);
    }
}

__global__ __launch_bounds__(256) void k_scan_block2(const int* __restrict__ cu, int* __restrict__ rp_u,
                                                     const int* __restrict__ ci, int* __restrict__ rp_i,
                                                     int* __restrict__ bsums, int nbU, int NU, int NI) {
    __shared__ int ts[256];
    bool rel = blockIdx.x >= (unsigned)nbU;
    const int* in = rel ? ci : cu;
    int* out = rel ? rp_i : rp_u;
    int n = rel ? NI : NU;
    int boff = rel ? blockIdx.x - nbU : blockIdx.x;
    int t = threadIdx.x;
    int base = boff * 2048 + t * 8;
    int v[8]; int s = 0;
#pragma unroll
    for (int k = 0; k < 8; ++k) { int idx = base + k; v[k] = idx < n ? in[idx] : 0; s += v[k]; }
    ts[t] = s; __syncthreads();
    for (int off = 1; off < 256; off <<= 1) {
        int x = (t >= off) ? ts[t - off] : 0;
        __syncthreads(); ts[t] += x; __syncthreads();
    }
    int excl = ts[t] - s;
    if (t == 255) bsums[blockIdx.x] = ts[255];
    int run = excl;
#pragma unroll
    for (int k = 0; k < 8; ++k) { int idx = base + k; if (idx < n) out[idx] = run; run += v[k]; }
}

// in-place exclusive scan of bsums, two segments [0,nbU) and [nbU,nbU+nbI), each <=128
__global__ __launch_bounds__(256) void k_scan_small(int* __restrict__ bsums, int nbU, int nbI) {
    __shared__ int ts[256];
    int t = threadIdx.x;
    int half = t >> 7, local = t & 127;
    int nb = half ? nbI : nbU;
    int g = half ? nbU + local : local;
    int v = local < nb ? bsums[g] : 0;
    ts[t] = v; __syncthreads();
    for (int off = 1; off < 128; off <<= 1) {
        int x = (local >= off) ? ts[t - off] : 0;
        __syncthreads(); ts[t] += x; __syncthreads();
    }
    if (local < nb) bsums[g] = ts[t] - v;
}

__global__ __launch_bounds__(256) void k_fixup2(int* __restrict__ rp_u, int* __restrict__ rp_i,
                                                const int* __restrict__ bsums,
                                                int* __restrict__ cu, int* __restrict__ ci,
                                                int NU, int NI, int E, int nbU) {
    int i = blockIdx.x * blockDim.x + threadIdx.x;
    if (i < NU) {
        int v = rp_u[i] + bsums[i >> 11]; rp_u[i] = v; cu[i] = v;
        if (i == 0) rp_u[NU] = E;
    } else if (i < NU + NI) {
        int j = i - NU;
        int v = rp_i[j] + bsums[nbU + (j >> 11)]; rp_i[j] = v; ci[j] = v;
        if (j == 0) rp_i[NI] = E;
    }
}

// scatter into dst-sorted order; (src,time) packed as int2
__global__ __launch_bounds__(256) void k_scatter2(
    const int* __restrict__ bs, const int* __restrict__ bd, const float* __restrict__ bt,
    const int* __restrict__ ps, const int* __restrict__ pd, const float* __restrict__ pt,
    int* __restrict__ cu, int* __restrict__ ci,
    int2* __restrict__ bst, int* __restrict__ bdo_,
    int2* __restrict__ pst, int* __restrict__ pdo_, int E) {
    for (int i = blockIdx.x * blockDim.x + threadIdx.x; i < 2 * E; i += gridDim.x * blockDim.x) {
        if (i < E) {
            int d = bd[i]; int pos = atomicAdd(&cu[d], 1);
            bst[pos] = make_int2(bs[i], __float_as_int(bt[i])); bdo_[pos] = d;
        } else {
            int k = i - E;
            int d = pd[k]; int pos = atomicAdd(&ci[d], 1);
            pst[pos] = make_int2(ps[k], __float_as_int(pt[k])); pdo_[pos] = d;
        }
    }
}

// ============================ transform: W-in-VGPR (pinned), broadcast-row GEMM ====================
// Lane j holds W[:, j] in 64 VGPRs; asm keep-live pins them so the compiler cannot
// sink the W loads into the row loop (round-7 lesson: it re-loaded W per row).
__global__ __launch_bounds__(256) void k_transform3(
    const float* __restrict__ user_h, const float* __restrict__ item_h,
    const float* __restrict__ Wu_l, const float* __restrict__ Wi_l,
    unsigned short* __restrict__ uh, unsigned short* __restrict__ ih,
    int NU, int NI, int G) {
    bool rel = blockIdx.x >= (unsigned)G;
    int b = rel ? blockIdx.x - G : blockIdx.x;
    const float* in = rel ? item_h : user_h;
    const float* W  = rel ? Wi_l : Wu_l;
    unsigned short* out = rel ? ih : uh;
    int n = rel ? NI : NU;
    int lane = threadIdx.x & 63;
    int gw = b * 4 + (threadIdx.x >> 6);      // wave id within table
    int nw = G * 4;                           // waves per table
    float w[D];
#pragma unroll
    for (int d = 0; d < D; ++d) w[d] = W[d * D + lane];
#pragma unroll
    for (int d = 0; d < D; ++d) asm volatile("" : "+v"(w[d]));  // pin in VGPRs
    for (int row = gw; row < n; row += nw) {
        const float4* rp = (const float4*)&in[(size_t)row * D];
        float acc0 = 0.f, acc1 = 0.f;
#pragma unroll
        for (int c = 0; c < 8; ++c) {
            float4 va = rp[2 * c];                // same addr across lanes -> broadcast
            float4 vb = rp[2 * c + 1];
            acc0 = fmaf(va.x, w[8 * c + 0], acc0);
            acc0 = fmaf(va.y, w[8 * c + 1], acc0);
            acc0 = fmaf(va.z, w[8 * c + 2], acc0);
            acc0 = fmaf(va.w, w[8 * c + 3], acc0);
            acc1 = fmaf(vb.x, w[8 * c + 4], acc1);
            acc1 = fmaf(vb.y, w[8 * c + 5], acc1);
            acc1 = fmaf(vb.z, w[8 * c + 6], acc1);
            acc1 = fmaf(vb.w, w[8 * c + 7], acc1);
        }
        out[(size_t)row * D + lane] = f2bf(acc0 + acc1);
    }
}

// ============================ edge kernel: 16-lane groups, strided dims ============================
// Lane covers dims {l, l+16, l+32, l+48}: each atomic-flush instruction writes
// 16 lanes x 4B contiguous = one fully-dirty 64B line (round-5 write-amplification fix).
__global__ __launch_bounds__(256) void k_edge2(
    const unsigned short* __restrict__ ihF, const unsigned short* __restrict__ uhF,
    const int2* __restrict__ by_st, const int* __restrict__ by_d,
    const int2* __restrict__ pby_st, const int* __restrict__ pby_d,
    const float* __restrict__ uf, const float* __restrict__ up,
    const float* __restrict__ ukf, const float* __restrict__ ukp,
    const float* __restrict__ ifq, const float* __restrict__ ipq,
    const float* __restrict__ ikf, const float* __restrict__ ikp,
    float* __restrict__ agg_u, float* __restrict__ den_u,
    float* __restrict__ agg_i, float* __restrict__ den_i,
    int E, int EB) {
    bool rel = blockIdx.x >= (unsigned)EB;  // false: 'by' item->user, true: 'pby' user->item
    int rblk = rel ? blockIdx.x - EB : blockIdx.x;
    const unsigned short* srcF = rel ? uhF : ihF;
    const unsigned short* dstF = rel ? ihF : uhF;
    const int2* est = rel ? pby_st : by_st;
    const int* ed = rel ? pby_d : by_d;
    const float* efq = rel ? ifq : uf;
    const float* eps = rel ? ipq : up;
    const float* kfq = rel ? ikf : ukf;
    const float* kps = rel ? ikp : ukp;
    float* agg = rel ? agg_i : agg_u;
    float* den = rel ? den_i : den_u;

    int lane = threadIdx.x & 15;
    int grp  = threadIdx.x >> 4;
    int base = rblk * 256 + grp * 16;
    if (base >= E) return;
    float ef0 = efq[lane], ef1 = efq[lane + 16], ef2 = efq[lane + 32], ef3 = efq[lane + 48];
    float ep0 = eps[lane], ep1 = eps[lane + 16], ep2 = eps[lane + 32], ep3 = eps[lane + 48];
    float kf0 = kfq[lane], kf1 = kfq[lane + 16], kf2 = kfq[lane + 32], kf3 = kfq[lane + 48];
    float kp0 = kps[lane], kp1 = kps[lane + 16], kp2 = kps[lane + 32], kp3 = kps[lane + 48];
    bool same = ef0 == kf0 && ef1 == kf1 && ef2 == kf2 && ef3 == kf3 &&
                ep0 == kp0 && ep1 == kp1 && ep2 == kp2 && ep3 == kp3;
    same = __all(same);  // uniform: key time-encode identical to e time-encode

    float a0 = 0, a1 = 0, a2 = 0, a3 = 0, dn = 0;
    float d0 = 0, d1 = 0, d2 = 0, d3 = 0;
    int cur = -1;
    for (int j = 0; j < 16; ++j) {
        int e = base + j;
        if (e >= E) break;
        int2 st = est[e];
        int s = st.x; float t = __int_as_float(st.y);
        int dd = ed[e];
        if (dd != cur) {  // group-uniform
            if (cur >= 0) {
                float* ap = &agg[(size_t)cur * D + lane];
                unsafeAtomicAdd(ap +  0, a0); unsafeAtomicAdd(ap + 16, a1);
                unsafeAtomicAdd(ap + 32, a2); unsafeAtomicAdd(ap + 48, a3);
                if (lane == 0) unsafeAtomicAdd(&den[cur], dn);
            }
            a0 = a1 = a2 = a3 = 0; dn = 0; cur = dd;
            const unsigned short* dp = &dstF[(size_t)dd * D + lane];
            d0 = bf2f(dp[0]); d1 = bf2f(dp[16]); d2 = bf2f(dp[32]); d3 = bf2f(dp[48]);
        }
        const unsigned short* sp = &srcF[(size_t)s * D + lane];
        float s0 = bf2f(sp[0]), s1 = bf2f(sp[16]), s2 = bf2f(sp[32]), s3 = bf2f(sp[48]);
        float c0 = __cosf(fmaf(t, ef0, ep0));
        float c1 = __cosf(fmaf(t, ef1, ep1));
        float c2 = __cosf(fmaf(t, ef2, ep2));
        float c3 = __cosf(fmaf(t, ef3, ep3));
        float p = (c0 + s0) * d0 + (c1 + s1) * d1 + (c2 + s2) * d2 + (c3 + s3) * d3;
        p += __shfl_xor(p, 1); p += __shfl_xor(p, 2);
        p += __shfl_xor(p, 4); p += __shfl_xor(p, 8);
        float ex = __expf(p * 0.125f);
        float k0, k1, k2, k3;
        if (same) { k0 = c0; k1 = c1; k2 = c2; k3 = c3; }
        else {
            k0 = __cosf(fmaf(t, kf0, kp0)); k1 = __cosf(fmaf(t, kf1, kp1));
            k2 = __cosf(fmaf(t, kf2, kp2)); k3 = __cosf(fmaf(t, kf3, kp3));
        }
        a0 = fmaf(ex, s0 + k0, a0); a1 = fmaf(ex, s1 + k1, a1);
        a2 = fmaf(ex, s2 + k2, a2); a3 = fmaf(ex, s3 + k3, a3);
        dn += ex;
    }
    if (cur >= 0) {
        float* ap = &agg[(size_t)cur * D + lane];
        unsafeAtomicAdd(ap +  0, a0); unsafeAtomicAdd(ap + 16, a1);
        unsafeAtomicAdd(ap + 32, a2); unsafeAtomicAdd(ap + 48, a3);
        if (lane == 0) unsafeAtomicAdd(&den[cur], dn);
    }
}

// ============================ update: W2-in-VGPR (pinned 128), broadcast-row, ELU ================
__global__ __launch_bounds__(256) void k_update3(
    float* __restrict__ user_h, float* __restrict__ item_h,
    const float* __restrict__ agg_u, const float* __restrict__ den_u,
    const float* __restrict__ agg_i, const float* __restrict__ den_i,
    const float* __restrict__ Wuu_l, const float* __restrict__ Wii_l,
    int NU, int NI, int G) {
    bool rel = blockIdx.x >= (unsigned)G;
    int b = rel ? blockIdx.x - G : blockIdx.x;
    float* h = rel ? item_h : user_h;
    const float* agg = rel ? agg_i : agg_u;
    const float* den = rel ? den_i : den_u;
    const float* W2  = rel ? Wii_l : Wuu_l;
    int n = rel ? NI : NU;
    int lane = threadIdx.x & 63;
    int gw = b * 4 + (threadIdx.x >> 6);
    int nw = G * 4;
    float w[2 * D];
#pragma unroll
    for (int d = 0; d < 2 * D; ++d) w[d] = W2[d * D + lane];
#pragma unroll
    for (int d = 0; d < 2 * D; ++d) asm volatile("" : "+v"(w[d]));  // pin in VGPRs
    for (int row = gw; row < n; row += nw) {
        const float4* ar = (const float4*)&agg[(size_t)row * D];
        const float4* hr = (const float4*)&h[(size_t)row * D];
        float dd = den[row];
        float inv = dd > 0.f ? 1.f / dd : 0.f;   // empty segment -> agg contribution 0
        float a0 = 0.f, a1 = 0.f, h0 = 0.f, h1 = 0.f;
#pragma unroll
        for (int c = 0; c < 8; ++c) {
            float4 va = ar[2 * c];               // broadcast
            float4 vb = ar[2 * c + 1];
            a0 = fmaf(va.x, w[8 * c + 0], a0);
            a0 = fmaf(va.y, w[8 * c + 1], a0);
            a0 = fmaf(va.z, w[8 * c + 2], a0);
            a0 = fmaf(va.w, w[8 * c + 3], a0);
            a1 = fmaf(vb.x, w[8 * c + 4], a1);
            a1 = fmaf(vb.y, w[8 * c + 5], a1);
            a1 = fmaf(vb.z, w[8 * c + 6], a1);
            a1 = fmaf(vb.w, w[8 * c + 7], a1);
        }
#pragma unroll
        for (int c = 0; c < 8; ++c) {
            float4 va = hr[2 * c];               // broadcast
            float4 vb = hr[2 * c + 1];
            h0 = fmaf(va.x, w[D + 8 * c + 0], h0);
            h0 = fmaf(va.y, w[D + 8 * c + 1], h0);
            h0 = fmaf(va.z, w[D + 8 * c + 2], h0);
            h0 = fmaf(va.w, w[D + 8 * c + 3], h0);
            h1 = fmaf(vb.x, w[D + 8 * c + 4], h1);
            h1 = fmaf(vb.y, w[D + 8 * c + 5], h1);
            h1 = fmaf(vb.z, w[D + 8 * c + 6], h1);
            h1 = fmaf(vb.w, w[D + 8 * c + 7], h1);
        }
        float o = (a0 + a1) * inv + (h0 + h1);
        h[(size_t)row * D + lane] = o > 0.f ? o : __expf(o) - 1.f;  // elu
    }
}

// ============================ tail ============================
__global__ __launch_bounds__(256) void k_gather_feat(const float* __restrict__ h,
                                                     const int* __restrict__ idx,
                                                     float* __restrict__ feat, int B,
                                                     int colOff, int FW) {
    int i = blockIdx.x * blockDim.x + threadIdx.x;
    if (i >= B * D) return;
    int b = i >> 6, c = i & 63;
    feat[(size_t)b * FW + colOff + c] = h[(size_t)idx[b] * D + c];
}

__global__ __launch_bounds__(64) void k_final(const float* __restrict__ feat,
                                              const float* __restrict__ uW,
                                              const float* __restrict__ dW,
                                              const float* __restrict__ db,
                                              float* __restrict__ out, int B, int FW) {
    __shared__ float fr[512];
    __shared__ float un[D];
    int b = blockIdx.x;
    int c = threadIdx.x;
    for (int i = c; i < FW; i += 64) fr[i] = feat[(size_t)b * FW + i];
    __syncthreads();
    float acc = 0.f;
    for (int d = 0; d < FW; ++d) acc += fr[d] * uW[d * D + c];
    un[c] = acc;
    __syncthreads();
    if (c < 3) {
        float o = db[c];
#pragma unroll
        for (int d = 0; d < D; ++d) o += un[d] * dW[d * 3 + c];
        out[b * 3 + c] = o > 0.f ? o : 0.f;
    }
}

// ============================ launch ============================
extern "C" void kernel_launch(void* const* d_in, const int* in_sizes, int n_in,
                              void* d_out, int out_size, void* d_ws, size_t ws_size,
                              hipStream_t stream) {
    const float* user_emb = (const float*)d_in[0];
    const float* item_emb = (const float*)d_in[1];
    const float* Wu       = (const float*)d_in[2];
    const float* Wi       = (const float*)d_in[3];
    const float* Wuu      = (const float*)d_in[4];
    const float* Wii      = (const float*)d_in[5];
    const float* u_freq   = (const float*)d_in[6];
    const float* u_phase  = (const float*)d_in[7];
    const float* uk_freq  = (const float*)d_in[8];
    const float* uk_phase = (const float*)d_in[9];
    const float* i_freq   = (const float*)d_in[10];
    const float* i_phase  = (const float*)d_in[11];
    const float* ik_freq  = (const float*)d_in[12];
    const float* ik_phase = (const float*)d_in[13];
    const float* unified_W = (const float*)d_in[14];
    const float* dense_W   = (const float*)d_in[15];
    const float* dense_b   = (const float*)d_in[16];
    const float* by_time   = (const float*)d_in[17];
    const float* pby_time  = (const float*)d_in[18];
    const int* user_id   = (const int*)d_in[19];
    const int* item_id   = (const int*)d_in[20];
    const int* by_src    = (const int*)d_in[21];
    const int* by_dst    = (const int*)d_in[22];
    const int* pby_src   = (const int*)d_in[23];
    const int* pby_dst   = (const int*)d_in[24];
    const int* user_index = (const int*)d_in[25];
    const int* last_item_index = (const int*)d_in[26];

    const int NU = in_sizes[19];
    const int NI = in_sizes[20];
    const int E  = in_sizes[21];
    const int B  = in_sizes[25];
    const int L  = in_sizes[2] / (D * D);
    const int FW = (L + 1) * D;

    // ---- workspace: [agg_u|agg_i|den_u|den_i] zeroed per layer; [cur_u|cur_i] zeroed once ----
    char* wp = (char*)d_ws;
    auto alloc_f = [&](size_t n) { float* p = (float*)wp; wp += n * sizeof(float); return p; };
    auto alloc_i = [&](size_t n) { int* p = (int*)wp; wp += n * sizeof(int); return p; };
    auto alloc_i2 = [&](size_t n) { int2* p = (int2*)wp; wp += n * sizeof(int2); return p; };
    auto alloc_h = [&](size_t n) { unsigned short* p = (unsigned short*)wp; wp += n * sizeof(unsigned short); return p; };
    float* agg_u = alloc_f((size_t)NU * D);
    float* agg_i = alloc_f((size_t)NI * D);
    float* den_u = alloc_f(NU);
    float* den_i = alloc_f(NI);
    size_t zero_bytes = (size_t)(wp - (char*)d_ws);
    int2* by_st  = alloc_i2(E);     // 8B-aligned (all prior sizes are multiples of 8)
    int2* pby_st = alloc_i2(E);
    int* cur_u = alloc_i(NU);
    int* cur_i = alloc_i(NI);
    size_t cur_bytes = (size_t)NU * 4 + (size_t)NI * 4;
    float* user_h = alloc_f((size_t)NU * D);
    float* item_h = alloc_f((size_t)NI * D);
    unsigned short* uh = alloc_h((size_t)NU * D);
    unsigned short* ih = alloc_h((size_t)NI * D);
    int*   by_dsts    = alloc_i(E);
    int*   pby_dsts   = alloc_i(E);
    int*   by_rowptr  = alloc_i(NU + 2);
    int*   pby_rowptr = alloc_i(NI + 2);
    int*   bsums      = alloc_i(512);
    float* feat       = alloc_f((size_t)B * FW);

    const int nbU = (NU + 2047) / 2048, nbI = (NI + 2047) / 2048;

    // initial node features
    k_gather2<<<((NU + NI) * D + 255) / 256, 256, 0, stream>>>(
        user_emb, item_emb, user_id, item_id, user_h, item_h, NU, NI);

    // dst-sorted edge lists, both relations
    hipMemsetAsync(cur_u, 0, cur_bytes, stream);
    k_hist2<<<2048, 256, 0, stream>>>(by_dst, pby_dst, cur_u, cur_i, E);
    k_scan_block2<<<nbU + nbI, 256, 0, stream>>>(cur_u, by_rowptr, cur_i, pby_rowptr,
                                                 bsums, nbU, NU, NI);
    k_scan_small<<<1, 256, 0, stream>>>(bsums, nbU, nbI);
    k_fixup2<<<(NU + NI + 255) / 256, 256, 0, stream>>>(by_rowptr, pby_rowptr, bsums,
                                                        cur_u, cur_i, NU, NI, E, nbU);
    k_scatter2<<<2048, 256, 0, stream>>>(by_src, by_dst, by_time,
                                         pby_src, pby_dst, pby_time,
                                         cur_u, cur_i,
                                         by_st, by_dsts,
                                         pby_st, pby_dsts, E);

    const int EB = (E + 255) / 256;
    const int GT = 640;  // transform blocks per table (~5 blocks/CU at ~90 VGPR)
    const int GU = 384;  // update blocks per table (~3 blocks/CU at ~150 VGPR)
    for (int l = 0; l < L; ++l) {
        hipMemsetAsync(d_ws, 0, zero_bytes, stream);
        k_transform3<<<2 * GT, 256, 0, stream>>>(user_h, item_h,
                                                 Wu + l * D * D, Wi + l * D * D,
                                                 uh, ih, NU, NI, GT);
        k_edge2<<<2 * EB, 256, 0, stream>>>(
            ih, uh,
            by_st, by_dsts,
            pby_st, pby_dsts,
            u_freq + l * D, u_phase + l * D, uk_freq + l * D, uk_phase + l * D,
            i_freq + l * D, i_phase + l * D, ik_freq + l * D, ik_phase + l * D,
            agg_u, den_u, agg_i, den_i, E, EB);
        k_update3<<<2 * GU, 256, 0, stream>>>(user_h, item_h,
                                              agg_u, den_u, agg_i, den_i,
                                              Wuu + (size_t)l * 2 * D * D,
                                              Wii + (size_t)l * 2 * D * D,
                                              NU, NI, GU);
        k_gather_feat<<<(B * D + 255) / 256, 256, 0, stream>>>(user_h, user_index, feat, B,
                                                               l * D, FW);
    }
    k_gather_feat<<<(B * D + 255) / 256, 256, 0, stream>>>(item_h, last_item_index, feat, B,
                                                           L * D, FW);
    k_final<<<B, 64, 0, stream>>>(feat, unified_W, dense_W, dense_b, (float*)d_out, B, FW);
}

// Round 9
// 732.905 us; speedup vs baseline: 2.3222x; 2.3222x over previous
//
#include <hip/hip_runtime.h>
#include <math.h>

#define D 64

typedef __attribute__((ext_vector_type(8))) short s8bf;   // 8 x bf16 (4 VGPR) MFMA A/B frag
typedef __attribute__((ext_vector_type(4))) float fx4;    // 4 x f32 MFMA C/D frag

__device__ __forceinline__ float bf2f(unsigned short u) {
    union { unsigned int i; float f; } v; v.i = ((unsigned int)u) << 16; return v.f;
}
__device__ __forceinline__ unsigned short f2bf(float f) {
    union { float f; unsigned int i; } v; v.f = f;
    unsigned int r = v.i + 0x7FFFu + ((v.i >> 16) & 1u);
    return (unsigned short)(r >> 16);
}

// ============================ initial gather (both tables, one launch) ============================
__global__ __launch_bounds__(256) void k_gather2(const float* __restrict__ ue,
                                                 const float* __restrict__ ie,
                                                 const int* __restrict__ uid,
                                                 const int* __restrict__ iid,
                                                 float* __restrict__ uh0,
                                                 float* __restrict__ ih0, int NU, int NI) {
    int i = blockIdx.x * blockDim.x + threadIdx.x;
    if (i >= (NU + NI) * D) return;
    int r = i >> 6, c = i & 63;
    if (r < NU) uh0[(size_t)r * D + c] = ue[(size_t)uid[r] * D + c];
    else { int j = r - NU; ih0[(size_t)j * D + c] = ie[(size_t)iid[j] * D + c]; }
}

// ============================ weight transpose+bf16 prep (once) ============================
// WuT/WiT[l][c][k] (64x64), WuuT/WiiT[l][c][k] (64x128) -- B operand wants W^T contiguous in k
__global__ __launch_bounds__(256) void k_wprep(const float* __restrict__ Wu,
                                               const float* __restrict__ Wi,
                                               const float* __restrict__ Wuu,
                                               const float* __restrict__ Wii,
                                               unsigned short* __restrict__ WuT,
                                               unsigned short* __restrict__ WiT,
                                               unsigned short* __restrict__ WuuT,
                                               unsigned short* __restrict__ WiiT, int L) {
    int i = blockIdx.x * blockDim.x + threadIdx.x;
    int n1 = L * 64 * 64, n2 = L * 64 * 128;
    if (i < n1) {
        int l = i >> 12, c = (i >> 6) & 63, k = i & 63;
        WuT[i] = f2bf(Wu[l * 4096 + k * 64 + c]);
        WiT[i] = f2bf(Wi[l * 4096 + k * 64 + c]);
    }
    if (i < n2) {
        int l = i >> 13, c = (i >> 7) & 63, k = i & 127;
        WuuT[i] = f2bf(Wuu[l * 8192 + k * 64 + c]);
        WiiT[i] = f2bf(Wii[l * 8192 + k * 64 + c]);
    }
}

// ============================ CSR build (both relations per launch) ============================
__global__ __launch_bounds__(256) void k_hist2(const int* __restrict__ bd,
                                               const int* __restrict__ pd,
                                               int* __restrict__ cu, int* __restrict__ ci, int E) {
    for (int i = blockIdx.x * blockDim.x + threadIdx.x; i < 2 * E; i += gridDim.x * blockDim.x) {
        if (i < E) atomicAdd(&cu[bd[i]], 1);
        else       atomicAdd(&ci[pd[i - E]], 1);
    }
}

__global__ __launch_bounds__(256) void k_scan_block2(const int* __restrict__ cu, int* __restrict__ rp_u,
                                                     const int* __restrict__ ci, int* __restrict__ rp_i,
                                                     int* __restrict__ bsums, int nbU, int NU, int NI) {
    __shared__ int ts[256];
    bool rel = blockIdx.x >= (unsigned)nbU;
    const int* in = rel ? ci : cu;
    int* out = rel ? rp_i : rp_u;
    int n = rel ? NI : NU;
    int boff = rel ? blockIdx.x - nbU : blockIdx.x;
    int t = threadIdx.x;
    int base = boff * 2048 + t * 8;
    int v[8]; int s = 0;
#pragma unroll
    for (int k = 0; k < 8; ++k) { int idx = base + k; v[k] = idx < n ? in[idx] : 0; s += v[k]; }
    ts[t] = s; __syncthreads();
    for (int off = 1; off < 256; off <<= 1) {
        int x = (t >= off) ? ts[t - off] : 0;
        __syncthreads(); ts[t] += x; __syncthreads();
    }
    int excl = ts[t] - s;
    if (t == 255) bsums[blockIdx.x] = ts[255];
    int run = excl;
#pragma unroll
    for (int k = 0; k < 8; ++k) { int idx = base + k; if (idx < n) out[idx] = run; run += v[k]; }
}

__global__ __launch_bounds__(256) void k_scan_small(int* __restrict__ bsums, int nbU, int nbI) {
    __shared__ int ts[256];
    int t = threadIdx.x;
    int half = t >> 7, local = t & 127;
    int nb = half ? nbI : nbU;
    int g = half ? nbU + local : local;
    int v = local < nb ? bsums[g] : 0;
    ts[t] = v; __syncthreads();
    for (int off = 1; off < 128; off <<= 1) {
        int x = (local >= off) ? ts[t - off] : 0;
        __syncthreads(); ts[t] += x; __syncthreads();
    }
    if (local < nb) bsums[g] = ts[t] - v;
}

__global__ __launch_bounds__(256) void k_fixup2(int* __restrict__ rp_u, int* __restrict__ rp_i,
                                                const int* __restrict__ bsums,
                                                int* __restrict__ cu, int* __restrict__ ci,
                                                int NU, int NI, int E, int nbU) {
    int i = blockIdx.x * blockDim.x + threadIdx.x;
    if (i < NU) {
        int v = rp_u[i] + bsums[i >> 11]; rp_u[i] = v; cu[i] = v;
        if (i == 0) rp_u[NU] = E;
    } else if (i < NU + NI) {
        int j = i - NU;
        int v = rp_i[j] + bsums[nbU + (j >> 11)]; rp_i[j] = v; ci[j] = v;
        if (j == 0) rp_i[NI] = E;
    }
}

__global__ __launch_bounds__(256) void k_scatter2(
    const int* __restrict__ bs, const int* __restrict__ bd, const float* __restrict__ bt,
    const int* __restrict__ ps, const int* __restrict__ pd, const float* __restrict__ pt,
    int* __restrict__ cu, int* __restrict__ ci,
    int2* __restrict__ bst, int* __restrict__ bdo_,
    int2* __restrict__ pst, int* __restrict__ pdo_, int E) {
    for (int i = blockIdx.x * blockDim.x + threadIdx.x; i < 2 * E; i += gridDim.x * blockDim.x) {
        if (i < E) {
            int d = bd[i]; int pos = atomicAdd(&cu[d], 1);
            bst[pos] = make_int2(bs[i], __float_as_int(bt[i])); bdo_[pos] = d;
        } else {
            int k = i - E;
            int d = pd[k]; int pos = atomicAdd(&ci[d], 1);
            pst[pos] = make_int2(ps[k], __float_as_int(pt[k])); pdo_[pos] = d;
        }
    }
}

// ============================ transform: MFMA 16x16x32 bf16 ============================
// One wave per 16-row tile, grid-strided. A: in-rows f32->bf16; B: WT preloaded (8 frags).
// A layout: row=lane&15, k=(lane>>4)*8+j. B: col=lane&15, k=(lane>>4)*8+j (WT[c][k] contiguous).
// C: col=lane&15, row=(lane>>4)*4+reg  [guide m89].
__global__ __launch_bounds__(256) void k_transform4(
    const float* __restrict__ user_h, const float* __restrict__ item_h,
    const unsigned short* __restrict__ WuT_l, const unsigned short* __restrict__ WiT_l,
    unsigned short* __restrict__ uh, unsigned short* __restrict__ ih,
    int NU, int NI, int G) {
    bool rel = blockIdx.x >= (unsigned)G;
    int b = rel ? blockIdx.x - G : blockIdx.x;
    const float* in = rel ? item_h : user_h;
    const unsigned short* WT = rel ? WiT_l : WuT_l;
    unsigned short* out = rel ? ih : uh;
    int n = rel ? NI : NU;
    int lane = threadIdx.x & 63;
    int l15 = lane & 15, l4 = lane >> 4;
    s8bf bfr[8];
#pragma unroll
    for (int ct = 0; ct < 4; ++ct)
#pragma unroll
        for (int kk = 0; kk < 2; ++kk)
            bfr[ct * 2 + kk] = *(const s8bf*)&WT[(ct * 16 + l15) * 64 + kk * 32 + l4 * 8];
    int wave = b * 4 + (threadIdx.x >> 6);
    int nw = G * 4;
    int ntiles = (n + 15) >> 4;
    for (int t = wave; t < ntiles; t += nw) {
        int r = t * 16 + l15; if (r >= n) r = n - 1;
        s8bf afr[2];
#pragma unroll
        for (int kk = 0; kk < 2; ++kk) {
            const float4* ap = (const float4*)&in[(size_t)r * 64 + kk * 32 + l4 * 8];
            float4 x = ap[0], y = ap[1];
            s8bf f;
            f[0] = (short)f2bf(x.x); f[1] = (short)f2bf(x.y);
            f[2] = (short)f2bf(x.z); f[3] = (short)f2bf(x.w);
            f[4] = (short)f2bf(y.x); f[5] = (short)f2bf(y.y);
            f[6] = (short)f2bf(y.z); f[7] = (short)f2bf(y.w);
            afr[kk] = f;
        }
#pragma unroll
        for (int ct = 0; ct < 4; ++ct) {
            fx4 c = {0.f, 0.f, 0.f, 0.f};
            c = __builtin_amdgcn_mfma_f32_16x16x32_bf16(afr[0], bfr[ct * 2 + 0], c, 0, 0, 0);
            c = __builtin_amdgcn_mfma_f32_16x16x32_bf16(afr[1], bfr[ct * 2 + 1], c, 0, 0, 0);
#pragma unroll
            for (int i2 = 0; i2 < 4; ++i2) {
                int row = t * 16 + l4 * 4 + i2;
                if (row < n) out[(size_t)row * 64 + ct * 16 + l15] = f2bf(c[i2]);
            }
        }
    }
}

// ============================ edge kernel: 16-lane groups, strided dims ============================
__global__ __launch_bounds__(256) void k_edge2(
    const unsigned short* __restrict__ ihF, const unsigned short* __restrict__ uhF,
    const int2* __restrict__ by_st, const int* __restrict__ by_d,
    const int2* __restrict__ pby_st, const int* __restrict__ pby_d,
    const float* __restrict__ uf, const float* __restrict__ up,
    const float* __restrict__ ukf, const float* __restrict__ ukp,
    const float* __restrict__ ifq, const float* __restrict__ ipq,
    const float* __restrict__ ikf, const float* __restrict__ ikp,
    float* __restrict__ agg_u, float* __restrict__ den_u,
    float* __restrict__ agg_i, float* __restrict__ den_i,
    int E, int EB) {
    bool rel = blockIdx.x >= (unsigned)EB;  // false: 'by' item->user, true: 'pby' user->item
    int rblk = rel ? blockIdx.x - EB : blockIdx.x;
    const unsigned short* srcF = rel ? uhF : ihF;
    const unsigned short* dstF = rel ? ihF : uhF;
    const int2* est = rel ? pby_st : by_st;
    const int* ed = rel ? pby_d : by_d;
    const float* efq = rel ? ifq : uf;
    const float* eps = rel ? ipq : up;
    const float* kfq = rel ? ikf : ukf;
    const float* kps = rel ? ikp : ukp;
    float* agg = rel ? agg_i : agg_u;
    float* den = rel ? den_i : den_u;

    int lane = threadIdx.x & 15;
    int grp  = threadIdx.x >> 4;
    int base = rblk * 256 + grp * 16;
    if (base >= E) return;
    float ef0 = efq[lane], ef1 = efq[lane + 16], ef2 = efq[lane + 32], ef3 = efq[lane + 48];
    float ep0 = eps[lane], ep1 = eps[lane + 16], ep2 = eps[lane + 32], ep3 = eps[lane + 48];
    float kf0 = kfq[lane], kf1 = kfq[lane + 16], kf2 = kfq[lane + 32], kf3 = kfq[lane + 48];
    float kp0 = kps[lane], kp1 = kps[lane + 16], kp2 = kps[lane + 32], kp3 = kps[lane + 48];
    bool same = ef0 == kf0 && ef1 == kf1 && ef2 == kf2 && ef3 == kf3 &&
                ep0 == kp0 && ep1 == kp1 && ep2 == kp2 && ep3 == kp3;
    same = __all(same);

    float a0 = 0, a1 = 0, a2 = 0, a3 = 0, dn = 0;
    float d0 = 0, d1 = 0, d2 = 0, d3 = 0;
    int cur = -1;
    for (int j = 0; j < 16; ++j) {
        int e = base + j;
        if (e >= E) break;
        int2 st = est[e];
        int s = st.x; float t = __int_as_float(st.y);
        int dd = ed[e];
        if (dd != cur) {  // group-uniform
            if (cur >= 0) {
                float* ap = &agg[(size_t)cur * D + lane];
                unsafeAtomicAdd(ap +  0, a0); unsafeAtomicAdd(ap + 16, a1);
                unsafeAtomicAdd(ap + 32, a2); unsafeAtomicAdd(ap + 48, a3);
                if (lane == 0) unsafeAtomicAdd(&den[cur], dn);
            }
            a0 = a1 = a2 = a3 = 0; dn = 0; cur = dd;
            const unsigned short* dp = &dstF[(size_t)dd * D + lane];
            d0 = bf2f(dp[0]); d1 = bf2f(dp[16]); d2 = bf2f(dp[32]); d3 = bf2f(dp[48]);
        }
        const unsigned short* sp = &srcF[(size_t)s * D + lane];
        float s0 = bf2f(sp[0]), s1 = bf2f(sp[16]), s2 = bf2f(sp[32]), s3 = bf2f(sp[48]);
        float c0 = __cosf(fmaf(t, ef0, ep0));
        float c1 = __cosf(fmaf(t, ef1, ep1));
        float c2 = __cosf(fmaf(t, ef2, ep2));
        float c3 = __cosf(fmaf(t, ef3, ep3));
        float p = (c0 + s0) * d0 + (c1 + s1) * d1 + (c2 + s2) * d2 + (c3 + s3) * d3;
        p += __shfl_xor(p, 1); p += __shfl_xor(p, 2);
        p += __shfl_xor(p, 4); p += __shfl_xor(p, 8);
        float ex = __expf(p * 0.125f);
        float k0, k1, k2, k3;
        if (same) { k0 = c0; k1 = c1; k2 = c2; k3 = c3; }
        else {
            k0 = __cosf(fmaf(t, kf0, kp0)); k1 = __cosf(fmaf(t, kf1, kp1));
            k2 = __cosf(fmaf(t, kf2, kp2)); k3 = __cosf(fmaf(t, kf3, kp3));
        }
        a0 = fmaf(ex, s0 + k0, a0); a1 = fmaf(ex, s1 + k1, a1);
        a2 = fmaf(ex, s2 + k2, a2); a3 = fmaf(ex, s3 + k3, a3);
        dn += ex;
    }
    if (cur >= 0) {
        float* ap = &agg[(size_t)cur * D + lane];
        unsafeAtomicAdd(ap +  0, a0); unsafeAtomicAdd(ap + 16, a1);
        unsafeAtomicAdd(ap + 32, a2); unsafeAtomicAdd(ap + 48, a3);
        if (lane == 0) unsafeAtomicAdd(&den[cur], dn);
    }
}

// ============================ update: MFMA 16x16x32 bf16, K=128, in-place ELU =====================
// A = [agg*inv | h] per row (f32->bf16 in-flight); B = W2T preloaded (16 frags).
// In-place safe: one wave owns its 16 rows; all A reads precede stores.
__global__ __launch_bounds__(256) void k_update4(
    float* __restrict__ user_h, float* __restrict__ item_h,
    const float* __restrict__ agg_u, const float* __restrict__ den_u,
    const float* __restrict__ agg_i, const float* __restrict__ den_i,
    const unsigned short* __restrict__ WuuT_l, const unsigned short* __restrict__ WiiT_l,
    int NU, int NI, int G) {
    bool rel = blockIdx.x >= (unsigned)G;
    int b = rel ? blockIdx.x - G : blockIdx.x;
    float* h = rel ? item_h : user_h;
    const float* agg = rel ? agg_i : agg_u;
    const float* den = rel ? den_i : den_u;
    const unsigned short* WT = rel ? WiiT_l : WuuT_l;
    int n = rel ? NI : NU;
    int lane = threadIdx.x & 63;
    int l15 = lane & 15, l4 = lane >> 4;
    s8bf bfr[16];
#pragma unroll
    for (int ct = 0; ct < 4; ++ct)
#pragma unroll
        for (int kk = 0; kk < 4; ++kk)
            bfr[ct * 4 + kk] = *(const s8bf*)&WT[(ct * 16 + l15) * 128 + kk * 32 + l4 * 8];
    int wave = b * 4 + (threadIdx.x >> 6);
    int nw = G * 4;
    int ntiles = (n + 15) >> 4;
    for (int t = wave; t < ntiles; t += nw) {
        int r = t * 16 + l15; if (r >= n) r = n - 1;
        float dd = den[r];
        float inv = dd > 0.f ? 1.f / dd : 0.f;   // empty segment -> agg contribution 0
        s8bf afr[4];
#pragma unroll
        for (int kk = 0; kk < 2; ++kk) {         // agg half (k in [0,64))
            const float4* ap = (const float4*)&agg[(size_t)r * 64 + kk * 32 + l4 * 8];
            float4 x = ap[0], y = ap[1];
            s8bf f;
            f[0] = (short)f2bf(x.x * inv); f[1] = (short)f2bf(x.y * inv);
            f[2] = (short)f2bf(x.z * inv); f[3] = (short)f2bf(x.w * inv);
            f[4] = (short)f2bf(y.x * inv); f[5] = (short)f2bf(y.y * inv);
            f[6] = (short)f2bf(y.z * inv); f[7] = (short)f2bf(y.w * inv);
            afr[kk] = f;
        }
#pragma unroll
        for (int kk = 0; kk < 2; ++kk) {         // h half (k in [64,128))
            const float4* hp = (const float4*)&h[(size_t)r * 64 + kk * 32 + l4 * 8];
            float4 x = hp[0], y = hp[1];
            s8bf f;
            f[0] = (short)f2bf(x.x); f[1] = (short)f2bf(x.y);
            f[2] = (short)f2bf(x.z); f[3] = (short)f2bf(x.w);
            f[4] = (short)f2bf(y.x); f[5] = (short)f2bf(y.y);
            f[6] = (short)f2bf(y.z); f[7] = (short)f2bf(y.w);
            afr[2 + kk] = f;
        }
#pragma unroll
        for (int ct = 0; ct < 4; ++ct) {
            fx4 c = {0.f, 0.f, 0.f, 0.f};
            c = __builtin_amdgcn_mfma_f32_16x16x32_bf16(afr[0], bfr[ct * 4 + 0], c, 0, 0, 0);
            c = __builtin_amdgcn_mfma_f32_16x16x32_bf16(afr[1], bfr[ct * 4 + 1], c, 0, 0, 0);
            c = __builtin_amdgcn_mfma_f32_16x16x32_bf16(afr[2], bfr[ct * 4 + 2], c, 0, 0, 0);
            c = __builtin_amdgcn_mfma_f32_16x16x32_bf16(afr[3], bfr[ct * 4 + 3], c, 0, 0, 0);
#pragma unroll
            for (int i2 = 0; i2 < 4; ++i2) {
                int row = t * 16 + l4 * 4 + i2;
                if (row < n) {
                    float o = c[i2];
                    h[(size_t)row * 64 + ct * 16 + l15] = o > 0.f ? o : __expf(o) - 1.f;
                }
            }
        }
    }
}

// ============================ tail ============================
__global__ __launch_bounds__(256) void k_gather_feat(const float* __restrict__ h,
                                                     const int* __restrict__ idx,
                                                     float* __restrict__ feat, int B,
                                                     int colOff, int FW) {
    int i = blockIdx.x * blockDim.x + threadIdx.x;
    if (i >= B * D) return;
    int b = i >> 6, c = i & 63;
    feat[(size_t)b * FW + colOff + c] = h[(size_t)idx[b] * D + c];
}

__global__ __launch_bounds__(64) void k_final(const float* __restrict__ feat,
                                              const float* __restrict__ uW,
                                              const float* __restrict__ dW,
                                              const float* __restrict__ db,
                                              float* __restrict__ out, int B, int FW) {
    __shared__ float fr[512];
    __shared__ float un[D];
    int b = blockIdx.x;
    int c = threadIdx.x;
    for (int i = c; i < FW; i += 64) fr[i] = feat[(size_t)b * FW + i];
    __syncthreads();
    float acc = 0.f;
    for (int d = 0; d < FW; ++d) acc += fr[d] * uW[d * D + c];
    un[c] = acc;
    __syncthreads();
    if (c < 3) {
        float o = db[c];
#pragma unroll
        for (int d = 0; d < D; ++d) o += un[d] * dW[d * 3 + c];
        out[b * 3 + c] = o > 0.f ? o : 0.f;
    }
}

// ============================ launch ============================
extern "C" void kernel_launch(void* const* d_in, const int* in_sizes, int n_in,
                              void* d_out, int out_size, void* d_ws, size_t ws_size,
                              hipStream_t stream) {
    const float* user_emb = (const float*)d_in[0];
    const float* item_emb = (const float*)d_in[1];
    const float* Wu       = (const float*)d_in[2];
    const float* Wi       = (const float*)d_in[3];
    const float* Wuu      = (const float*)d_in[4];
    const float* Wii      = (const float*)d_in[5];
    const float* u_freq   = (const float*)d_in[6];
    const float* u_phase  = (const float*)d_in[7];
    const float* uk_freq  = (const float*)d_in[8];
    const float* uk_phase = (const float*)d_in[9];
    const float* i_freq   = (const float*)d_in[10];
    const float* i_phase  = (const float*)d_in[11];
    const float* ik_freq  = (const float*)d_in[12];
    const float* ik_phase = (const float*)d_in[13];
    const float* unified_W = (const float*)d_in[14];
    const float* dense_W   = (const float*)d_in[15];
    const float* dense_b   = (const float*)d_in[16];
    const float* by_time   = (const float*)d_in[17];
    const float* pby_time  = (const float*)d_in[18];
    const int* user_id   = (const int*)d_in[19];
    const int* item_id   = (const int*)d_in[20];
    const int* by_src    = (const int*)d_in[21];
    const int* by_dst    = (const int*)d_in[22];
    const int* pby_src   = (const int*)d_in[23];
    const int* pby_dst   = (const int*)d_in[24];
    const int* user_index = (const int*)d_in[25];
    const int* last_item_index = (const int*)d_in[26];

    const int NU = in_sizes[19];
    const int NI = in_sizes[20];
    const int E  = in_sizes[21];
    const int B  = in_sizes[25];
    const int L  = in_sizes[2] / (D * D);
    const int FW = (L + 1) * D;

    // ---- workspace: [agg_u|agg_i|den_u|den_i] zeroed per layer; [cur_u|cur_i] zeroed once ----
    char* wp = (char*)d_ws;
    auto alloc_f = [&](size_t n) { float* p = (float*)wp; wp += n * sizeof(float); return p; };
    auto alloc_i = [&](size_t n) { int* p = (int*)wp; wp += n * sizeof(int); return p; };
    auto alloc_i2 = [&](size_t n) { int2* p = (int2*)wp; wp += n * sizeof(int2); return p; };
    auto alloc_h = [&](size_t n) { unsigned short* p = (unsigned short*)wp; wp += n * sizeof(unsigned short); return p; };
    float* agg_u = alloc_f((size_t)NU * D);
    float* agg_i = alloc_f((size_t)NI * D);
    float* den_u = alloc_f(NU);
    float* den_i = alloc_f(NI);
    size_t zero_bytes = (size_t)(wp - (char*)d_ws);
    int2* by_st  = alloc_i2(E);
    int2* pby_st = alloc_i2(E);
    int* cur_u = alloc_i(NU);
    int* cur_i = alloc_i(NI);
    size_t cur_bytes = (size_t)NU * 4 + (size_t)NI * 4;
    float* user_h = alloc_f((size_t)NU * D);
    float* item_h = alloc_f((size_t)NI * D);
    unsigned short* uh = alloc_h((size_t)NU * D);
    unsigned short* ih = alloc_h((size_t)NI * D);
    unsigned short* WuT  = alloc_h((size_t)L * 64 * 64);
    unsigned short* WiT  = alloc_h((size_t)L * 64 * 64);
    unsigned short* WuuT = alloc_h((size_t)L * 64 * 128);
    unsigned short* WiiT = alloc_h((size_t)L * 64 * 128);
    int*   by_dsts    = alloc_i(E);
    int*   pby_dsts   = alloc_i(E);
    int*   by_rowptr  = alloc_i(NU + 2);
    int*   pby_rowptr = alloc_i(NI + 2);
    int*   bsums      = alloc_i(512);
    float* feat       = alloc_f((size_t)B * FW);

    const int nbU = (NU + 2047) / 2048, nbI = (NI + 2047) / 2048;

    // initial node features + weight prep
    k_gather2<<<((NU + NI) * D + 255) / 256, 256, 0, stream>>>(
        user_emb, item_emb, user_id, item_id, user_h, item_h, NU, NI);
    k_wprep<<<(L * 64 * 128 + 255) / 256, 256, 0, stream>>>(Wu, Wi, Wuu, Wii,
                                                            WuT, WiT, WuuT, WiiT, L);

    // dst-sorted edge lists, both relations
    hipMemsetAsync(cur_u, 0, cur_bytes, stream);
    k_hist2<<<2048, 256, 0, stream>>>(by_dst, pby_dst, cur_u, cur_i, E);
    k_scan_block2<<<nbU + nbI, 256, 0, stream>>>(cur_u, by_rowptr, cur_i, pby_rowptr,
                                                 bsums, nbU, NU, NI);
    k_scan_small<<<1, 256, 0, stream>>>(bsums, nbU, nbI);
    k_fixup2<<<(NU + NI + 255) / 256, 256, 0, stream>>>(by_rowptr, pby_rowptr, bsums,
                                                        cur_u, cur_i, NU, NI, E, nbU);
    k_scatter2<<<2048, 256, 0, stream>>>(by_src, by_dst, by_time,
                                         pby_src, pby_dst, pby_time,
                                         cur_u, cur_i,
                                         by_st, by_dsts,
                                         pby_st, pby_dsts, E);

    const int EB = (E + 255) / 256;
    const int GM = 512;  // MFMA kernel blocks per table
    for (int l = 0; l < L; ++l) {
        hipMemsetAsync(d_ws, 0, zero_bytes, stream);
        k_transform4<<<2 * GM, 256, 0, stream>>>(user_h, item_h,
                                                 WuT + (size_t)l * 4096, WiT + (size_t)l * 4096,
                                                 uh, ih, NU, NI, GM);
        k_edge2<<<2 * EB, 256, 0, stream>>>(
            ih, uh,
            by_st, by_dsts,
            pby_st, pby_dsts,
            u_freq + l * D, u_phase + l * D, uk_freq + l * D, uk_phase + l * D,
            i_freq + l * D, i_phase + l * D, ik_freq + l * D, ik_phase + l * D,
            agg_u, den_u, agg_i, den_i, E, EB);
        k_update4<<<2 * GM, 256, 0, stream>>>(user_h, item_h,
                                              agg_u, den_u, agg_i, den_i,
                                              WuuT + (size_t)l * 8192, WiiT + (size_t)l * 8192,
                                              NU, NI, GM);
        k_gather_feat<<<(B * D + 255) / 256, 256, 0, stream>>>(user_h, user_index, feat, B,
                                                               l * D, FW);
    }
    k_gather_feat<<<(B * D + 255) / 256, 256, 0, stream>>>(item_h, last_item_index, feat, B,
                                                           L * D, FW);
    k_final<<<B, 64, 0, stream>>>(feat, unified_W, dense_W, dense_b, (float*)d_out, B, FW);
}